// Round 13
// baseline (194.917 us; speedup 1.0000x reference)
//
#include <hip/hip_runtime.h>
#include <hip/hip_bf16.h>

typedef __attribute__((ext_vector_type(2)))  float f32x2;
typedef __attribute__((ext_vector_type(4)))  float f32x4;
typedef __attribute__((ext_vector_type(16))) float f32x16;
typedef __attribute__((ext_vector_type(8)))  short s16x8;
typedef __attribute__((ext_vector_type(4)))  unsigned int u32x4;
typedef __attribute__((ext_vector_type(2)))  int i32x2;

#define D_MODEL 1024
#define D_HEAD  64
#define SEQ_T   4096

__device__ __forceinline__ unsigned short f2bf(float f) {
    unsigned int u = __float_as_uint(f);
    u += 0x7fffu + ((u >> 16) & 1u);
    return (unsigned short)(u >> 16);
}

__device__ __forceinline__ unsigned int cvtpk_bf16(float lo, float hi) {
    unsigned int r;
    asm("v_cvt_pk_bf16_f32 %0, %1, %2" : "=v"(r) : "v"(lo), "v"(hi));
    return r;
}

// raw 2^x (single v_exp_f32).  Scores are computed in log2 domain (log2e
// folded into the q pre-scale), so no per-element multiply is needed.
__device__ __forceinline__ float ex2(float x) {
#if __has_builtin(__builtin_amdgcn_exp2f)
    return __builtin_amdgcn_exp2f(x);
#else
    return exp2f(x);
#endif
}

// lane l <-> lane l^32 exchange.  Returns BOTH post-exchange words: per lane
// {r0, r1} == {x[l], x[l^32]} (order may be lane-dependent).  Consumers use
// order-agnostic ops (fmax/add) or r0^r1^x for the partner.  SSA builtin ->
// distinct result registers, no aliasing.  PROVEN round 10.
__device__ __forceinline__ void halfswap(unsigned int x,
                                         unsigned int& r0, unsigned int& r1) {
#if __has_builtin(__builtin_amdgcn_permlane32_swap)
    i32x2 r = __builtin_amdgcn_permlane32_swap((int)x, (int)x, false, false);
    r0 = (unsigned int)r[0];
    r1 = (unsigned int)r[1];
#else
    r0 = x;
    r1 = (unsigned int)__shfl_xor((int)x, 32);       // proven fallback
#endif
}

__device__ __forceinline__ f32x4 mfma16(s16x8 a, s16x8 b, f32x4 c) {
    return __builtin_amdgcn_mfma_f32_16x16x32_bf16(a, b, c, 0, 0, 0);
}
__device__ __forceinline__ f32x16 mfma32(s16x8 a, s16x8 b, f32x16 c) {
    return __builtin_amdgcn_mfma_f32_32x32x16_bf16(a, b, c, 0, 0, 0);
}

// ---------------------------------------------------------------------------
// Kernel 0: weights [1024][64] f32 (q,k,v) -> wT [192][1024] bf16 (transposed)
// ---------------------------------------------------------------------------
__global__ __launch_bounds__(256) void wconv_kernel(
    const float* __restrict__ wq, const float* __restrict__ wk,
    const float* __restrict__ wv, unsigned short* __restrict__ wT)
{
    int idx = blockIdx.x * 256 + threadIdx.x;        // [0, 3*65536)
    int mat = idx >> 16;
    int rem = idx & 65535;
    int k = rem >> 6, n = rem & 63;
    const float* w = (mat == 0) ? wq : (mat == 1) ? wk : wv;
    wT[(size_t)(mat * 64 + n) * D_MODEL + k] = f2bf(w[rem]);
}

// ---------------------------------------------------------------------------
// Kernel 1: fused QKV projection — 2-phase LDS GEMM (proven ~24us).
// STRIDES MUST KEEP 16B ROW ALIGNMENT: x [64][68] f32, wT [96][72] bf16.
// q pre-scaled by log2e/8.  v written transposed: vT[b][d][t].
// ---------------------------------------------------------------------------
#define XSTR 68
#define WSTR 72
__global__ __launch_bounds__(256, 2) void qkv_kernel(
    const float* __restrict__ x,
    const float* __restrict__ bq, const float* __restrict__ bk,
    const float* __restrict__ bv,
    const unsigned short* __restrict__ wT,
    unsigned short* __restrict__ q_ws, unsigned short* __restrict__ k_ws,
    unsigned short* __restrict__ vT_ws)
{
    __shared__ float xs[2][64 * XSTR];               // 2 x 17408 B
    __shared__ unsigned short wls[2][96 * WSTR];     // 2 x 13824 B (61 KiB)
    const int t = threadIdx.x;
    const int lane = t & 63, w = t >> 6;
    const int wr = w >> 1, wc = w & 1;
    const int lr = lane & 15, lg = lane >> 4;
    const int mb = (int)blockIdx.x >> 1, nb = (int)blockIdx.x & 1;

    const float* xsrc = x + (size_t)(mb * 64 + (t >> 4)) * D_MODEL + (t & 15) * 4;
    const unsigned short* wsrc = wT + (size_t)(nb * 96 + (t >> 3)) * D_MODEL + (t & 7) * 8;

    f32x4 acc[2][3];
#pragma unroll
    for (int s = 0; s < 2; ++s)
#pragma unroll
        for (int c = 0; c < 3; ++c) acc[s][c] = (f32x4)0.0f;

    f32x4 xreg[4];
    u32x4 wreg[3];

#define GLOAD(K0) do {                                                         \
    _Pragma("unroll") for (int j = 0; j < 4; ++j)                              \
        xreg[j] = *(const f32x4*)(xsrc + (size_t)j * 16 * D_MODEL + (K0));     \
    _Pragma("unroll") for (int j = 0; j < 3; ++j)                              \
        wreg[j] = *(const u32x4*)(wsrc + (size_t)j * 32 * D_MODEL + (K0));     \
} while (0)

#define DSWRITE(BUF) do {                                                      \
    float* XB = &xs[BUF][0]; unsigned short* WB = &wls[BUF][0];                \
    _Pragma("unroll") for (int j = 0; j < 4; ++j)                              \
        *(f32x4*)(XB + ((t >> 4) + j * 16) * XSTR + (t & 15) * 4) = xreg[j];   \
    _Pragma("unroll") for (int j = 0; j < 3; ++j)                              \
        *(u32x4*)(WB + ((t >> 3) + j * 32) * WSTR + (t & 7) * 8) = wreg[j];    \
} while (0)

#define COMPUTE(BUF) do {                                                      \
    const float* XB = &xs[BUF][0]; const unsigned short* WB = &wls[BUF][0];    \
    _Pragma("unroll") for (int ks = 0; ks < 2; ++ks) {                         \
        s16x8 af[2];                                                           \
        _Pragma("unroll") for (int sub = 0; sub < 2; ++sub) {                  \
            const float* ap = XB + (wr * 32 + sub * 16 + lr) * XSTR + ks * 32 + lg * 8; \
            f32x4 a0 = *(const f32x4*)ap, a1 = *(const f32x4*)(ap + 4);        \
            u32x4 pk;                                                          \
            pk[0] = cvtpk_bf16(a0[0], a0[1]); pk[1] = cvtpk_bf16(a0[2], a0[3]);\
            pk[2] = cvtpk_bf16(a1[0], a1[1]); pk[3] = cvtpk_bf16(a1[2], a1[3]);\
            af[sub] = __builtin_bit_cast(s16x8, pk);                           \
        }                                                                      \
        _Pragma("unroll") for (int tc = 0; tc < 3; ++tc) {                     \
            s16x8 bf = *(const s16x8*)(WB + (wc * 48 + tc * 16 + lr) * WSTR + ks * 32 + lg * 8); \
            acc[0][tc] = mfma16(af[0], bf, acc[0][tc]);                        \
            acc[1][tc] = mfma16(af[1], bf, acc[1][tc]);                        \
        }                                                                      \
    }                                                                          \
} while (0)

    // prologue: stage tile 0, issue tile 1
    GLOAD(0);
    DSWRITE(0);
    GLOAD(64);
    __syncthreads();

    for (int step = 0; step < 16; ++step) {
        const int cur = step & 1;
        if (step + 1 < 16) DSWRITE(cur ^ 1);         // write next tile (regs ready)
        if (step + 2 < 16) GLOAD((step + 2) * 64);   // issue loads 2 steps ahead
        COMPUTE(cur);
        __syncthreads();                             // one barrier per K-step
    }

#undef GLOAD
#undef DSWRITE
#undef COMPUTE

    // epilogue: bias + dtype-split writes
#pragma unroll
    for (int sub = 0; sub < 2; ++sub)
#pragma unroll
        for (int tc = 0; tc < 3; ++tc) {
            int col = nb * 96 + wc * 48 + tc * 16 + lr;
            float bias = (col < 64) ? bq[col] : (col < 128) ? bk[col - 64] : bv[col - 128];
#pragma unroll
            for (int r = 0; r < 4; ++r) {
                int row = mb * 64 + wr * 32 + sub * 16 + lg * 4 + r;   // = b*4096 + t
                float v = acc[sub][tc][r] + bias;
                if (col < 64) {
                    // scale = 1/sqrt(64) * log2(e): softmax in exp2 domain
                    q_ws[(size_t)row * 64 + col] = f2bf(v * 0.18033688011112042f);
                } else if (col < 128) {
                    k_ws[(size_t)row * 64 + (col - 64)] = f2bf(v);
                } else {
                    int b = row >> 12, tt = row & 4095;
                    vT_ws[(size_t)(b * 64 + (col - 128)) * SEQ_T + tt] = f2bf(v);
                }
            }
        }
}

// ---------------------------------------------------------------------------
// Kernel 2: causal flash attention, swapped-QK in-register softmax (32x32),
// exp2-domain.  Grid 512: block = (h, batch b, pair p); each (b,p) pair's
// 129 KV-tiles are split across the TWO h-blocks via interleaved slots
// slot = 2w + h (keeps both blocks at 129/2 +-1 tiles) -> 2 blocks/CU
// (LDS 2x71.7KB = 143KB), 8 waves/SIMD (VGPR pinned 64 via launch_bounds).
// Each block combines its 16 waves and writes an UNNORMALIZED partial
// (O[64], m, l) per q-row; merge_kernel combines the h-pairs.
// ---------------------------------------------------------------------------
__global__ __launch_bounds__(1024, 8) void attn_kernel(
    const unsigned short* __restrict__ q_ws, const unsigned short* __restrict__ k_ws,
    const unsigned short* __restrict__ vT_ws, float* __restrict__ part)
{
    __shared__ float solds[8][32][66];               // 67.6 KiB
    __shared__ float sml[16][2][32];                 // 4 KiB
    const int lane = threadIdx.x & 63;
    const int w = threadIdx.x >> 6;                  // 0..15
    const int q = lane & 31;
    const int hi = lane >> 5;
    const int khalf = 4 * hi;
    // XCD-batch swizzle: XCD = bid%8; bits 1-2 -> batch (pins each batch's
    // K/V to one XCD pair); bit 0 -> h (KV-split half); high bits -> p.
    const int h = (int)blockIdx.x & 1;
    const int b = ((int)blockIdx.x & 7) >> 1;
    const int p = (int)blockIdx.x >> 3;              // 0..63
    const int slot = 2 * w + h;                      // interleaved: balance +-1

#define PUBLISH(SLOT) do {                                                     \
    _Pragma("unroll") for (int i = 0; i < 16; ++i) {                           \
        int d = (i & 3) + 8 * (i >> 2) + khalf;                                \
        solds[SLOT][q][d] = o0[i];                                             \
        solds[SLOT][q][d + 32] = o1[i];                                        \
    }                                                                          \
    if (!hi) { sml[w][0][q] = m; sml[w][1][q] = lsum; }                        \
} while (0)

#define MERGE(SLOT, PW) do {                                                   \
    float mp = sml[PW][0][q], lp = sml[PW][1][q];                              \
    float M = fmaxf(m, mp);                                                    \
    float e = ex2(m - M), ep = ex2(mp - M);                                    \
    m = M; lsum = lsum * e + lp * ep;                                          \
    _Pragma("unroll") for (int i = 0; i < 16; ++i) {                           \
        int d = (i & 3) + 8 * (i >> 2) + khalf;                                \
        o0[i] = o0[i] * e + solds[SLOT][q][d] * ep;                            \
        o1[i] = o1[i] * e + solds[SLOT][q][d + 32] * ep;                       \
    }                                                                          \
} while (0)

    for (int half = 0; half < 2; ++half) {
        const int qb = (half == 0) ? p : 127 - p;
        const int q0 = SEQ_T - 32 * (qb + 1);
        const int ntiles = (q0 >> 5) + 1;

        const unsigned short* qrow = q_ws + ((size_t)(b * SEQ_T + q0 + q)) * 64 + hi * 8;
        s16x8 qf[4];
#pragma unroll
        for (int d = 0; d < 4; ++d) qf[d] = *(const s16x8*)(qrow + d * 16);

        f32x16 o0 = (f32x16)0.0f, o1 = (f32x16)0.0f;
        float m = -1e30f, lsum = 0.0f;

        const unsigned short* kbase = k_ws + ((size_t)(b * SEQ_T + q)) * 64 + hi * 8;
        const unsigned short* vb0 = vT_ws + ((size_t)(b * 64 + q)) * SEQ_T + hi * 8;
        const unsigned short* vb1 = vT_ws + ((size_t)(b * 64 + 32 + q)) * SEQ_T + hi * 8;

        int c = slot;
        if (c < ntiles) {
            s16x8 kf[4];
            {
                const unsigned short* kp = kbase + (size_t)(c << 5) * 64;
#pragma unroll
                for (int d = 0; d < 4; ++d) kf[d] = *(const s16x8*)(kp + d * 16);
            }
            for (; c < ntiles; c += 32) {
                const int kv = c << 5;
                // ---- S^T = K Q^T (log2 domain) ----
                f32x16 s = (f32x16)0.0f;
#pragma unroll
                for (int d = 0; d < 4; ++d) s = mfma32(kf[d], qf[d], s);
                // ---- prefetch next K tile (stride 32) ----
                {
                    const int cn = (c + 32 < ntiles) ? c + 32 : 0;
                    const unsigned short* kp = kbase + (size_t)(cn << 5) * 64;
#pragma unroll
                    for (int d = 0; d < 4; ++d) kf[d] = *(const s16x8*)(kp + d * 16);
                }
                // ---- V^T A-fragments (issued here, consumed after softmax) ----
                s16x8 vf00 = *(const s16x8*)(vb0 + kv);
                s16x8 vf01 = *(const s16x8*)(vb0 + kv + 16);
                s16x8 vf10 = *(const s16x8*)(vb1 + kv);
                s16x8 vf11 = *(const s16x8*)(vb1 + kv + 16);
                // ---- causal mask (diagonal tile only) ----
                if (kv + 32 > q0) {
                    const int qg = q0 + q;
#pragma unroll
                    for (int i = 0; i < 16; ++i) {
                        int kk = kv + (i & 3) + 8 * (i >> 2) + khalf;
                        if (kk > qg) s[i] = -1e30f;
                    }
                }
                // ---- row max: tree + half-exchange (order-agnostic) ----
                float t0, t1;
                t0 = fmaxf(s[0], s[1]);   t1 = fmaxf(s[2], s[3]);   t0 = fmaxf(t0, t1);
                t1 = fmaxf(s[4], s[5]);   t1 = fmaxf(t1, fmaxf(s[6], s[7]));
                float t2 = fmaxf(fmaxf(s[8], s[9]), fmaxf(s[10], s[11]));
                float t3 = fmaxf(fmaxf(s[12], s[13]), fmaxf(s[14], s[15]));
                float mx = fmaxf(fmaxf(t0, t1), fmaxf(t2, t3));
                {
                    unsigned int r0, r1;
                    halfswap(__float_as_uint(mx), r0, r1);
                    mx = fmaxf(__uint_as_float(r0), __uint_as_float(r1));
                }
                const float mnew = fmaxf(m, mx);
                const float corr = ex2(m - mnew);
                m = mnew;
                // ---- P = 2^(S - m), row sum ----
                float rs = 0.0f;
#pragma unroll
                for (int i = 0; i < 16; ++i) {
                    float pv = ex2(s[i] - mnew);
                    s[i] = pv;
                    rs += pv;
                }
                {
                    unsigned int r0, r1;
                    halfswap(__float_as_uint(rs), r0, r1);
                    rs = __uint_as_float(r0) + __uint_as_float(r1);
                }
                lsum = lsum * corr + rs;
#pragma unroll
                for (int i = 0; i < 16; ++i) { o0[i] *= corr; o1[i] *= corr; }
                // ---- pack P -> B-fragments (cvt_pk; partner via r0^r1^own) ----
                unsigned int cc[8], pc[8];
#pragma unroll
                for (int i = 0; i < 8; ++i) cc[i] = cvtpk_bf16(s[2 * i], s[2 * i + 1]);
#pragma unroll
                for (int i = 0; i < 8; ++i) {
                    unsigned int r0, r1;
                    halfswap(cc[i], r0, r1);
                    pc[i] = r0 ^ r1 ^ cc[i];         // partner word, any convention
                }
                u32x4 w0, w1;
                w0[0] = hi ? pc[2] : cc[0]; w0[1] = hi ? pc[3] : cc[1];
                w0[2] = hi ? cc[2] : pc[0]; w0[3] = hi ? cc[3] : pc[1];
                w1[0] = hi ? pc[6] : cc[4]; w1[1] = hi ? pc[7] : cc[5];
                w1[2] = hi ? cc[6] : pc[4]; w1[3] = hi ? cc[7] : pc[5];
                s16x8 pb0 = __builtin_bit_cast(s16x8, w0);
                s16x8 pb1 = __builtin_bit_cast(s16x8, w1);
                // ---- O^T += V^T P^T ----
                o0 = mfma32(vf00, pb0, o0);
                o0 = mfma32(vf01, pb1, o0);
                o1 = mfma32(vf10, pb0, o1);
                o1 = mfma32(vf11, pb1, o1);
            }
        }

        // ---- cascade combine: 16 -> 8 -> 4 -> 1 ----
        if (w >= 8) PUBLISH(w - 8);
        __syncthreads();
        if (w < 8) MERGE(w, w + 8);
        __syncthreads();
        if (w >= 4 && w < 8) PUBLISH(w - 4);
        __syncthreads();
        if (w < 4) { MERGE(w, w + 4); PUBLISH(w); }
        __syncthreads();
        // ---- write UNNORMALIZED partial: O[64], m, l per q-row ----
        {
            const int qq = (int)threadIdx.x >> 5;
            const int dd = ((int)threadIdx.x & 31) * 2;
            float M = -1e30f;
#pragma unroll
            for (int ww = 0; ww < 4; ++ww) M = fmaxf(M, sml[ww][0][qq]);
            float L = 0.0f, O0 = 0.0f, O1 = 0.0f;
#pragma unroll
            for (int ww = 0; ww < 4; ++ww) {
                float e = ex2(sml[ww][0][qq] - M);
                L += sml[ww][1][qq] * e;
                O0 += solds[ww][qq][dd] * e;
                O1 += solds[ww][qq][dd + 1] * e;
            }
            const size_t r = (size_t)(b * SEQ_T + q0 + qq);
            float* pr = part + ((size_t)h * 16384 + r) * 68;
            f32x2 res; res[0] = O0; res[1] = O1;
            *(f32x2*)(pr + dd) = res;
            if (dd == 0) { pr[64] = M; pr[65] = L; }
        }
        __syncthreads();                             // solds reused by next half
    }
#undef PUBLISH
#undef MERGE
}

// ---------------------------------------------------------------------------
// Kernel 3: merge the two KV-split partials per q-row and normalize.
// 16384 rows x 64 d; thread handles 4 d-values of one row.
// ---------------------------------------------------------------------------
__global__ __launch_bounds__(256) void merge_kernel(
    const float* __restrict__ part, float* __restrict__ out)
{
    const int t = (int)blockIdx.x * 256 + (int)threadIdx.x;   // 0..262143
    const int r = t >> 4;
    const int dg = (t & 15) * 4;
    const float* p0 = part + (size_t)r * 68;
    const float* p1 = part + (size_t)(16384 + r) * 68;
    const float m0 = p0[64], l0 = p0[65];
    const float m1 = p1[64], l1 = p1[65];
    const float M = fmaxf(m0, m1);
    const float e0 = ex2(m0 - M), e1 = ex2(m1 - M);
    const float inv = 1.0f / (l0 * e0 + l1 * e1);
    f32x4 a = *(const f32x4*)(p0 + dg);
    f32x4 b = *(const f32x4*)(p1 + dg);
    f32x4 res;
#pragma unroll
    for (int j = 0; j < 4; ++j) res[j] = (a[j] * e0 + b[j] * e1) * inv;
    *(f32x4*)(out + (size_t)r * 64 + dg) = res;
}

// ---------------------------------------------------------------------------
extern "C" void kernel_launch(void* const* d_in, const int* in_sizes, int n_in,
                              void* d_out, int out_size, void* d_ws, size_t ws_size,
                              hipStream_t stream) {
    const float* x  = (const float*)d_in[0];
    const float* wq = (const float*)d_in[1];
    const float* bq = (const float*)d_in[2];
    const float* wk = (const float*)d_in[3];
    const float* bk = (const float*)d_in[4];
    const float* wv = (const float*)d_in[5];
    const float* bv = (const float*)d_in[6];
    float* out = (float*)d_out;

    char* ws = (char*)d_ws;
    unsigned short* wT    = (unsigned short*)(ws);                       // 384 KiB
    unsigned short* q_ws  = (unsigned short*)(ws + 393216);              // 2 MiB
    unsigned short* k_ws  = (unsigned short*)(ws + 393216 + 2097152);    // 2 MiB
    unsigned short* vT_ws = (unsigned short*)(ws + 393216 + 2 * 2097152);// 2 MiB
    float* part = (float*)(ws + 393216 + 3 * 2097152);                   // 8.9 MiB

    wconv_kernel<<<dim3(768), dim3(256), 0, stream>>>(wq, wk, wv, wT);
    qkv_kernel<<<dim3(512), dim3(256), 0, stream>>>(x, bq, bk, bv, wT, q_ws, k_ws, vT_ws);
    attn_kernel<<<dim3(512), dim3(1024), 0, stream>>>(q_ws, k_ws, vT_ws, part);
    merge_kernel<<<dim3(1024), dim3(256), 0, stream>>>(part, out);
}

// Round 14
// 92.391 us; speedup vs baseline: 2.1097x; 2.1097x over previous
//
#include <hip/hip_runtime.h>
#include <hip/hip_bf16.h>

typedef __attribute__((ext_vector_type(2)))  float f32x2;
typedef __attribute__((ext_vector_type(4)))  float f32x4;
typedef __attribute__((ext_vector_type(16))) float f32x16;
typedef __attribute__((ext_vector_type(8)))  short s16x8;
typedef __attribute__((ext_vector_type(4)))  unsigned int u32x4;
typedef __attribute__((ext_vector_type(2)))  int i32x2;

#define D_MODEL 1024
#define D_HEAD  64
#define SEQ_T   4096

__device__ __forceinline__ unsigned short f2bf(float f) {
    unsigned int u = __float_as_uint(f);
    u += 0x7fffu + ((u >> 16) & 1u);
    return (unsigned short)(u >> 16);
}

__device__ __forceinline__ unsigned int cvtpk_bf16(float lo, float hi) {
    unsigned int r;
    asm("v_cvt_pk_bf16_f32 %0, %1, %2" : "=v"(r) : "v"(lo), "v"(hi));
    return r;
}

// raw 2^x (single v_exp_f32).  Scores are computed in log2 domain (log2e
// folded into the q pre-scale), so no per-element multiply is needed.
__device__ __forceinline__ float ex2(float x) {
#if __has_builtin(__builtin_amdgcn_exp2f)
    return __builtin_amdgcn_exp2f(x);
#else
    return exp2f(x);
#endif
}

// lane l <-> lane l^32 exchange.  Returns BOTH post-exchange words: per lane
// {r0, r1} == {x[l], x[l^32]} (order may be lane-dependent).  Consumers use
// order-agnostic ops (fmax/add) or r0^r1^x for the partner.  SSA builtin ->
// distinct result registers, no aliasing.  PROVEN round 10.
__device__ __forceinline__ void halfswap(unsigned int x,
                                         unsigned int& r0, unsigned int& r1) {
#if __has_builtin(__builtin_amdgcn_permlane32_swap)
    i32x2 r = __builtin_amdgcn_permlane32_swap((int)x, (int)x, false, false);
    r0 = (unsigned int)r[0];
    r1 = (unsigned int)r[1];
#else
    r0 = x;
    r1 = (unsigned int)__shfl_xor((int)x, 32);       // proven fallback
#endif
}

__device__ __forceinline__ f32x4 mfma16(s16x8 a, s16x8 b, f32x4 c) {
    return __builtin_amdgcn_mfma_f32_16x16x32_bf16(a, b, c, 0, 0, 0);
}
__device__ __forceinline__ f32x16 mfma32(s16x8 a, s16x8 b, f32x16 c) {
    return __builtin_amdgcn_mfma_f32_32x32x16_bf16(a, b, c, 0, 0, 0);
}

// ---------------------------------------------------------------------------
// Kernel 0: weights [1024][64] f32 (q,k,v) -> wT [192][1024] bf16 (transposed)
// ---------------------------------------------------------------------------
__global__ __launch_bounds__(256) void wconv_kernel(
    const float* __restrict__ wq, const float* __restrict__ wk,
    const float* __restrict__ wv, unsigned short* __restrict__ wT)
{
    int idx = blockIdx.x * 256 + threadIdx.x;        // [0, 3*65536)
    int mat = idx >> 16;
    int rem = idx & 65535;
    int k = rem >> 6, n = rem & 63;
    const float* w = (mat == 0) ? wq : (mat == 1) ? wk : wv;
    wT[(size_t)(mat * 64 + n) * D_MODEL + k] = f2bf(w[rem]);
}

// ---------------------------------------------------------------------------
// Kernel 1: fused QKV projection — 2-phase LDS GEMM (proven ~24us).
// STRIDES MUST KEEP 16B ROW ALIGNMENT: x [64][68] f32, wT [96][72] bf16.
// q pre-scaled by log2e/8.  v written transposed: vT[b][d][t].
// ---------------------------------------------------------------------------
#define XSTR 68
#define WSTR 72
__global__ __launch_bounds__(256, 2) void qkv_kernel(
    const float* __restrict__ x,
    const float* __restrict__ bq, const float* __restrict__ bk,
    const float* __restrict__ bv,
    const unsigned short* __restrict__ wT,
    unsigned short* __restrict__ q_ws, unsigned short* __restrict__ k_ws,
    unsigned short* __restrict__ vT_ws)
{
    __shared__ float xs[2][64 * XSTR];               // 2 x 17408 B
    __shared__ unsigned short wls[2][96 * WSTR];     // 2 x 13824 B (61 KiB)
    const int t = threadIdx.x;
    const int lane = t & 63, w = t >> 6;
    const int wr = w >> 1, wc = w & 1;
    const int lr = lane & 15, lg = lane >> 4;
    const int mb = (int)blockIdx.x >> 1, nb = (int)blockIdx.x & 1;

    const float* xsrc = x + (size_t)(mb * 64 + (t >> 4)) * D_MODEL + (t & 15) * 4;
    const unsigned short* wsrc = wT + (size_t)(nb * 96 + (t >> 3)) * D_MODEL + (t & 7) * 8;

    f32x4 acc[2][3];
#pragma unroll
    for (int s = 0; s < 2; ++s)
#pragma unroll
        for (int c = 0; c < 3; ++c) acc[s][c] = (f32x4)0.0f;

    f32x4 xreg[4];
    u32x4 wreg[3];

#define GLOAD(K0) do {                                                         \
    _Pragma("unroll") for (int j = 0; j < 4; ++j)                              \
        xreg[j] = *(const f32x4*)(xsrc + (size_t)j * 16 * D_MODEL + (K0));     \
    _Pragma("unroll") for (int j = 0; j < 3; ++j)                              \
        wreg[j] = *(const u32x4*)(wsrc + (size_t)j * 32 * D_MODEL + (K0));     \
} while (0)

#define DSWRITE(BUF) do {                                                      \
    float* XB = &xs[BUF][0]; unsigned short* WB = &wls[BUF][0];                \
    _Pragma("unroll") for (int j = 0; j < 4; ++j)                              \
        *(f32x4*)(XB + ((t >> 4) + j * 16) * XSTR + (t & 15) * 4) = xreg[j];   \
    _Pragma("unroll") for (int j = 0; j < 3; ++j)                              \
        *(u32x4*)(WB + ((t >> 3) + j * 32) * WSTR + (t & 7) * 8) = wreg[j];    \
} while (0)

#define COMPUTE(BUF) do {                                                      \
    const float* XB = &xs[BUF][0]; const unsigned short* WB = &wls[BUF][0];    \
    _Pragma("unroll") for (int ks = 0; ks < 2; ++ks) {                         \
        s16x8 af[2];                                                           \
        _Pragma("unroll") for (int sub = 0; sub < 2; ++sub) {                  \
            const float* ap = XB + (wr * 32 + sub * 16 + lr) * XSTR + ks * 32 + lg * 8; \
            f32x4 a0 = *(const f32x4*)ap, a1 = *(const f32x4*)(ap + 4);        \
            u32x4 pk;                                                          \
            pk[0] = cvtpk_bf16(a0[0], a0[1]); pk[1] = cvtpk_bf16(a0[2], a0[3]);\
            pk[2] = cvtpk_bf16(a1[0], a1[1]); pk[3] = cvtpk_bf16(a1[2], a1[3]);\
            af[sub] = __builtin_bit_cast(s16x8, pk);                           \
        }                                                                      \
        _Pragma("unroll") for (int tc = 0; tc < 3; ++tc) {                     \
            s16x8 bf = *(const s16x8*)(WB + (wc * 48 + tc * 16 + lr) * WSTR + ks * 32 + lg * 8); \
            acc[0][tc] = mfma16(af[0], bf, acc[0][tc]);                        \
            acc[1][tc] = mfma16(af[1], bf, acc[1][tc]);                        \
        }                                                                      \
    }                                                                          \
} while (0)

    // prologue: stage tile 0, issue tile 1
    GLOAD(0);
    DSWRITE(0);
    GLOAD(64);
    __syncthreads();

    for (int step = 0; step < 16; ++step) {
        const int cur = step & 1;
        if (step + 1 < 16) DSWRITE(cur ^ 1);         // write next tile (regs ready)
        if (step + 2 < 16) GLOAD((step + 2) * 64);   // issue loads 2 steps ahead
        COMPUTE(cur);
        __syncthreads();                             // one barrier per K-step
    }

#undef GLOAD
#undef DSWRITE
#undef COMPUTE

    // epilogue: bias + dtype-split writes
#pragma unroll
    for (int sub = 0; sub < 2; ++sub)
#pragma unroll
        for (int tc = 0; tc < 3; ++tc) {
            int col = nb * 96 + wc * 48 + tc * 16 + lr;
            float bias = (col < 64) ? bq[col] : (col < 128) ? bk[col - 64] : bv[col - 128];
#pragma unroll
            for (int r = 0; r < 4; ++r) {
                int row = mb * 64 + wr * 32 + sub * 16 + lg * 4 + r;   // = b*4096 + t
                float v = acc[sub][tc][r] + bias;
                if (col < 64) {
                    // scale = 1/sqrt(64) * log2(e): softmax in exp2 domain
                    q_ws[(size_t)row * 64 + col] = f2bf(v * 0.18033688011112042f);
                } else if (col < 128) {
                    k_ws[(size_t)row * 64 + (col - 64)] = f2bf(v);
                } else {
                    int b = row >> 12, tt = row & 4095;
                    vT_ws[(size_t)(b * 64 + (col - 128)) * SEQ_T + tt] = f2bf(v);
                }
            }
        }
}

// ---------------------------------------------------------------------------
// Kernel 2: causal flash attention, swapped-QK in-register softmax (32x32),
// exp2-domain.  Grid 512: block = (h, batch b, pair p); each (b,p) pair's
// 129 KV-tiles split across the TWO h-blocks via interleaved slots
// slot = 2w + h -> both blocks ~129/2 tiles.  LDS 71.7KB -> 2 blocks/CU fit;
// launch_bounds(1024,4) — the SOFT bound under which this loop is PROVEN to
// compile at 64 VGPR (round 12).  At 64 VGPR the HW co-schedules both
// blocks -> 8 waves/SIMD.  (1024,8)'s hard cap caused the round-13 spill
// catastrophe — never promise the allocator a ceiling it must die for.
// Each block writes an UNNORMALIZED partial (O[64], m, l) per q-row.
// ---------------------------------------------------------------------------
__global__ __launch_bounds__(1024, 4) void attn_kernel(
    const unsigned short* __restrict__ q_ws, const unsigned short* __restrict__ k_ws,
    const unsigned short* __restrict__ vT_ws, float* __restrict__ part)
{
    __shared__ float solds[8][32][66];               // 67.6 KiB
    __shared__ float sml[16][2][32];                 // 4 KiB
    const int lane = threadIdx.x & 63;
    const int w = threadIdx.x >> 6;                  // 0..15
    const int q = lane & 31;
    const int hi = lane >> 5;
    const int khalf = 4 * hi;
    // XCD-batch swizzle: XCD = bid%8; bits 1-2 -> batch (pins each batch's
    // K/V to one XCD pair); bit 0 -> h (KV-split half); high bits -> p.
    const int h = (int)blockIdx.x & 1;
    const int b = ((int)blockIdx.x & 7) >> 1;
    const int p = (int)blockIdx.x >> 3;              // 0..63
    const int slot = 2 * w + h;                      // interleaved: balance +-1

#define PUBLISH(SLOT) do {                                                     \
    _Pragma("unroll") for (int i = 0; i < 16; ++i) {                           \
        int d = (i & 3) + 8 * (i >> 2) + khalf;                                \
        solds[SLOT][q][d] = o0[i];                                             \
        solds[SLOT][q][d + 32] = o1[i];                                        \
    }                                                                          \
    if (!hi) { sml[w][0][q] = m; sml[w][1][q] = lsum; }                        \
} while (0)

#define MERGE(SLOT, PW) do {                                                   \
    float mp = sml[PW][0][q], lp = sml[PW][1][q];                              \
    float M = fmaxf(m, mp);                                                    \
    float e = ex2(m - M), ep = ex2(mp - M);                                    \
    m = M; lsum = lsum * e + lp * ep;                                          \
    _Pragma("unroll") for (int i = 0; i < 16; ++i) {                           \
        int d = (i & 3) + 8 * (i >> 2) + khalf;                                \
        o0[i] = o0[i] * e + solds[SLOT][q][d] * ep;                            \
        o1[i] = o1[i] * e + solds[SLOT][q][d + 32] * ep;                       \
    }                                                                          \
} while (0)

    for (int half = 0; half < 2; ++half) {
        const int qb = (half == 0) ? p : 127 - p;
        const int q0 = SEQ_T - 32 * (qb + 1);
        const int ntiles = (q0 >> 5) + 1;

        const unsigned short* qrow = q_ws + ((size_t)(b * SEQ_T + q0 + q)) * 64 + hi * 8;
        s16x8 qf[4];
#pragma unroll
        for (int d = 0; d < 4; ++d) qf[d] = *(const s16x8*)(qrow + d * 16);

        f32x16 o0 = (f32x16)0.0f, o1 = (f32x16)0.0f;
        float m = -1e30f, lsum = 0.0f;

        const unsigned short* kbase = k_ws + ((size_t)(b * SEQ_T + q)) * 64 + hi * 8;
        const unsigned short* vb0 = vT_ws + ((size_t)(b * 64 + q)) * SEQ_T + hi * 8;
        const unsigned short* vb1 = vT_ws + ((size_t)(b * 64 + 32 + q)) * SEQ_T + hi * 8;

        int c = slot;
        if (c < ntiles) {
            s16x8 kf[4];
            {
                const unsigned short* kp = kbase + (size_t)(c << 5) * 64;
#pragma unroll
                for (int d = 0; d < 4; ++d) kf[d] = *(const s16x8*)(kp + d * 16);
            }
            for (; c < ntiles; c += 32) {
                const int kv = c << 5;
                // ---- S^T = K Q^T (log2 domain) ----
                f32x16 s = (f32x16)0.0f;
#pragma unroll
                for (int d = 0; d < 4; ++d) s = mfma32(kf[d], qf[d], s);
                // ---- prefetch next K tile (stride 32) ----
                {
                    const int cn = (c + 32 < ntiles) ? c + 32 : 0;
                    const unsigned short* kp = kbase + (size_t)(cn << 5) * 64;
#pragma unroll
                    for (int d = 0; d < 4; ++d) kf[d] = *(const s16x8*)(kp + d * 16);
                }
                // ---- V^T A-fragments (issued here, consumed after softmax) ----
                s16x8 vf00 = *(const s16x8*)(vb0 + kv);
                s16x8 vf01 = *(const s16x8*)(vb0 + kv + 16);
                s16x8 vf10 = *(const s16x8*)(vb1 + kv);
                s16x8 vf11 = *(const s16x8*)(vb1 + kv + 16);
                // ---- causal mask (diagonal tile only) ----
                if (kv + 32 > q0) {
                    const int qg = q0 + q;
#pragma unroll
                    for (int i = 0; i < 16; ++i) {
                        int kk = kv + (i & 3) + 8 * (i >> 2) + khalf;
                        if (kk > qg) s[i] = -1e30f;
                    }
                }
                // ---- row max: tree + half-exchange (order-agnostic) ----
                float t0, t1;
                t0 = fmaxf(s[0], s[1]);   t1 = fmaxf(s[2], s[3]);   t0 = fmaxf(t0, t1);
                t1 = fmaxf(s[4], s[5]);   t1 = fmaxf(t1, fmaxf(s[6], s[7]));
                float t2 = fmaxf(fmaxf(s[8], s[9]), fmaxf(s[10], s[11]));
                float t3 = fmaxf(fmaxf(s[12], s[13]), fmaxf(s[14], s[15]));
                float mx = fmaxf(fmaxf(t0, t1), fmaxf(t2, t3));
                {
                    unsigned int r0, r1;
                    halfswap(__float_as_uint(mx), r0, r1);
                    mx = fmaxf(__uint_as_float(r0), __uint_as_float(r1));
                }
                const float mnew = fmaxf(m, mx);
                const float corr = ex2(m - mnew);
                m = mnew;
                // ---- P = 2^(S - m), row sum ----
                float rs = 0.0f;
#pragma unroll
                for (int i = 0; i < 16; ++i) {
                    float pv = ex2(s[i] - mnew);
                    s[i] = pv;
                    rs += pv;
                }
                {
                    unsigned int r0, r1;
                    halfswap(__float_as_uint(rs), r0, r1);
                    rs = __uint_as_float(r0) + __uint_as_float(r1);
                }
                lsum = lsum * corr + rs;
#pragma unroll
                for (int i = 0; i < 16; ++i) { o0[i] *= corr; o1[i] *= corr; }
                // ---- pack P -> B-fragments (cvt_pk; partner via r0^r1^own) ----
                unsigned int cc[8], pc[8];
#pragma unroll
                for (int i = 0; i < 8; ++i) cc[i] = cvtpk_bf16(s[2 * i], s[2 * i + 1]);
#pragma unroll
                for (int i = 0; i < 8; ++i) {
                    unsigned int r0, r1;
                    halfswap(cc[i], r0, r1);
                    pc[i] = r0 ^ r1 ^ cc[i];         // partner word, any convention
                }
                u32x4 w0, w1;
                w0[0] = hi ? pc[2] : cc[0]; w0[1] = hi ? pc[3] : cc[1];
                w0[2] = hi ? cc[2] : pc[0]; w0[3] = hi ? cc[3] : pc[1];
                w1[0] = hi ? pc[6] : cc[4]; w1[1] = hi ? pc[7] : cc[5];
                w1[2] = hi ? cc[6] : pc[4]; w1[3] = hi ? cc[7] : pc[5];
                s16x8 pb0 = __builtin_bit_cast(s16x8, w0);
                s16x8 pb1 = __builtin_bit_cast(s16x8, w1);
                // ---- O^T += V^T P^T ----
                o0 = mfma32(vf00, pb0, o0);
                o0 = mfma32(vf01, pb1, o0);
                o1 = mfma32(vf10, pb0, o1);
                o1 = mfma32(vf11, pb1, o1);
            }
        }

        // ---- cascade combine: 16 -> 8 -> 4 -> 1 ----
        if (w >= 8) PUBLISH(w - 8);
        __syncthreads();
        if (w < 8) MERGE(w, w + 8);
        __syncthreads();
        if (w >= 4 && w < 8) PUBLISH(w - 4);
        __syncthreads();
        if (w < 4) { MERGE(w, w + 4); PUBLISH(w); }
        __syncthreads();
        // ---- write UNNORMALIZED partial: O[64], m, l per q-row ----
        {
            const int qq = (int)threadIdx.x >> 5;
            const int dd = ((int)threadIdx.x & 31) * 2;
            float M = -1e30f;
#pragma unroll
            for (int ww = 0; ww < 4; ++ww) M = fmaxf(M, sml[ww][0][qq]);
            float L = 0.0f, O0 = 0.0f, O1 = 0.0f;
#pragma unroll
            for (int ww = 0; ww < 4; ++ww) {
                float e = ex2(sml[ww][0][qq] - M);
                L += sml[ww][1][qq] * e;
                O0 += solds[ww][qq][dd] * e;
                O1 += solds[ww][qq][dd + 1] * e;
            }
            const size_t r = (size_t)(b * SEQ_T + q0 + qq);
            float* pr = part + ((size_t)h * 16384 + r) * 68;
            f32x2 res; res[0] = O0; res[1] = O1;
            *(f32x2*)(pr + dd) = res;
            if (dd == 0) { pr[64] = M; pr[65] = L; }
        }
        __syncthreads();                             // solds reused by next half
    }
#undef PUBLISH
#undef MERGE
}

// ---------------------------------------------------------------------------
// Kernel 3: merge the two KV-split partials per q-row and normalize.
// 16384 rows x 64 d; thread handles 4 d-values of one row.
// ---------------------------------------------------------------------------
__global__ __launch_bounds__(256) void merge_kernel(
    const float* __restrict__ part, float* __restrict__ out)
{
    const int t = (int)blockIdx.x * 256 + (int)threadIdx.x;   // 0..262143
    const int r = t >> 4;
    const int dg = (t & 15) * 4;
    const float* p0 = part + (size_t)r * 68;
    const float* p1 = part + (size_t)(16384 + r) * 68;
    const float m0 = p0[64], l0 = p0[65];
    const float m1 = p1[64], l1 = p1[65];
    const float M = fmaxf(m0, m1);
    const float e0 = ex2(m0 - M), e1 = ex2(m1 - M);
    const float inv = 1.0f / (l0 * e0 + l1 * e1);
    f32x4 a = *(const f32x4*)(p0 + dg);
    f32x4 b = *(const f32x4*)(p1 + dg);
    f32x4 res;
#pragma unroll
    for (int j = 0; j < 4; ++j) res[j] = (a[j] * e0 + b[j] * e1) * inv;
    *(f32x4*)(out + (size_t)r * 64 + dg) = res;
}

// ---------------------------------------------------------------------------
extern "C" void kernel_launch(void* const* d_in, const int* in_sizes, int n_in,
                              void* d_out, int out_size, void* d_ws, size_t ws_size,
                              hipStream_t stream) {
    const float* x  = (const float*)d_in[0];
    const float* wq = (const float*)d_in[1];
    const float* bq = (const float*)d_in[2];
    const float* wk = (const float*)d_in[3];
    const float* bk = (const float*)d_in[4];
    const float* wv = (const float*)d_in[5];
    const float* bv = (const float*)d_in[6];
    float* out = (float*)d_out;

    char* ws = (char*)d_ws;
    unsigned short* wT    = (unsigned short*)(ws);                       // 384 KiB
    unsigned short* q_ws  = (unsigned short*)(ws + 393216);              // 2 MiB
    unsigned short* k_ws  = (unsigned short*)(ws + 393216 + 2097152);    // 2 MiB
    unsigned short* vT_ws = (unsigned short*)(ws + 393216 + 2 * 2097152);// 2 MiB
    float* part = (float*)(ws + 393216 + 3 * 2097152);                   // 8.9 MiB

    wconv_kernel<<<dim3(768), dim3(256), 0, stream>>>(wq, wk, wv, wT);
    qkv_kernel<<<dim3(512), dim3(256), 0, stream>>>(x, bq, bk, bv, wT, q_ws, k_ws, vT_ws);
    attn_kernel<<<dim3(512), dim3(1024), 0, stream>>>(q_ws, k_ws, vT_ws, part);
    merge_kernel<<<dim3(1024), dim3(256), 0, stream>>>(part, out);
}

// Round 16
// 77.313 us; speedup vs baseline: 2.5211x; 1.1950x over previous
//
#include <hip/hip_runtime.h>
#include <hip/hip_bf16.h>

typedef __attribute__((ext_vector_type(2)))  float f32x2;
typedef __attribute__((ext_vector_type(4)))  float f32x4;
typedef __attribute__((ext_vector_type(16))) float f32x16;
typedef __attribute__((ext_vector_type(8)))  short s16x8;
typedef __attribute__((ext_vector_type(4)))  unsigned int u32x4;
typedef __attribute__((ext_vector_type(2)))  int i32x2;

#define D_MODEL 1024
#define D_HEAD  64
#define SEQ_T   4096

__device__ __forceinline__ unsigned short f2bf(float f) {
    unsigned int u = __float_as_uint(f);
    u += 0x7fffu + ((u >> 16) & 1u);
    return (unsigned short)(u >> 16);
}

__device__ __forceinline__ unsigned int cvtpk_bf16(float lo, float hi) {
    unsigned int r;
    asm("v_cvt_pk_bf16_f32 %0, %1, %2" : "=v"(r) : "v"(lo), "v"(hi));
    return r;
}

// raw 2^x (single v_exp_f32).  Scores are computed in log2 domain (log2e
// folded into the q pre-scale), so no per-element multiply is needed.
__device__ __forceinline__ float ex2(float x) {
#if __has_builtin(__builtin_amdgcn_exp2f)
    return __builtin_amdgcn_exp2f(x);
#else
    return exp2f(x);
#endif
}

// lane l <-> lane l^32 exchange.  Returns BOTH post-exchange words: per lane
// {r0, r1} == {x[l], x[l^32]} (order may be lane-dependent).  Consumers use
// order-agnostic ops (fmax/add) or r0^r1^x for the partner.  SSA builtin ->
// distinct result registers, no aliasing.  PROVEN round 10/11/12.
__device__ __forceinline__ void halfswap(unsigned int x,
                                         unsigned int& r0, unsigned int& r1) {
#if __has_builtin(__builtin_amdgcn_permlane32_swap)
    i32x2 r = __builtin_amdgcn_permlane32_swap((int)x, (int)x, false, false);
    r0 = (unsigned int)r[0];
    r1 = (unsigned int)r[1];
#else
    r0 = x;
    r1 = (unsigned int)__shfl_xor((int)x, 32);       // proven fallback
#endif
}

__device__ __forceinline__ f32x4 mfma16(s16x8 a, s16x8 b, f32x4 c) {
    return __builtin_amdgcn_mfma_f32_16x16x32_bf16(a, b, c, 0, 0, 0);
}
__device__ __forceinline__ f32x16 mfma32(s16x8 a, s16x8 b, f32x16 c) {
    return __builtin_amdgcn_mfma_f32_32x32x16_bf16(a, b, c, 0, 0, 0);
}

// ---------------------------------------------------------------------------
// Kernel 0: weights [1024][64] f32 (q,k,v) -> wT [192][1024] bf16 (transposed)
// ---------------------------------------------------------------------------
__global__ __launch_bounds__(256) void wconv_kernel(
    const float* __restrict__ wq, const float* __restrict__ wk,
    const float* __restrict__ wv, unsigned short* __restrict__ wT)
{
    int idx = blockIdx.x * 256 + threadIdx.x;        // [0, 3*65536)
    int mat = idx >> 16;
    int rem = idx & 65535;
    int k = rem >> 6, n = rem & 63;
    const float* w = (mat == 0) ? wq : (mat == 1) ? wk : wv;
    wT[(size_t)(mat * 64 + n) * D_MODEL + k] = f2bf(w[rem]);
}

// ---------------------------------------------------------------------------
// Kernel 1: fused QKV projection — 2-phase LDS GEMM (proven ~24us).
// STRIDES MUST KEEP 16B ROW ALIGNMENT: x [64][68] f32, wT [96][72] bf16.
// q pre-scaled by log2e/8.  v written transposed: vT[b][d][t].
// ---------------------------------------------------------------------------
#define XSTR 68
#define WSTR 72
__global__ __launch_bounds__(256, 2) void qkv_kernel(
    const float* __restrict__ x,
    const float* __restrict__ bq, const float* __restrict__ bk,
    const float* __restrict__ bv,
    const unsigned short* __restrict__ wT,
    unsigned short* __restrict__ q_ws, unsigned short* __restrict__ k_ws,
    unsigned short* __restrict__ vT_ws)
{
    __shared__ float xs[2][64 * XSTR];               // 2 x 17408 B
    __shared__ unsigned short wls[2][96 * WSTR];     // 2 x 13824 B (61 KiB)
    const int t = threadIdx.x;
    const int lane = t & 63, w = t >> 6;
    const int wr = w >> 1, wc = w & 1;
    const int lr = lane & 15, lg = lane >> 4;
    const int mb = (int)blockIdx.x >> 1, nb = (int)blockIdx.x & 1;

    const float* xsrc = x + (size_t)(mb * 64 + (t >> 4)) * D_MODEL + (t & 15) * 4;
    const unsigned short* wsrc = wT + (size_t)(nb * 96 + (t >> 3)) * D_MODEL + (t & 7) * 8;

    f32x4 acc[2][3];
#pragma unroll
    for (int s = 0; s < 2; ++s)
#pragma unroll
        for (int c = 0; c < 3; ++c) acc[s][c] = (f32x4)0.0f;

    f32x4 xreg[4];
    u32x4 wreg[3];

#define GLOAD(K0) do {                                                         \
    _Pragma("unroll") for (int j = 0; j < 4; ++j)                              \
        xreg[j] = *(const f32x4*)(xsrc + (size_t)j * 16 * D_MODEL + (K0));     \
    _Pragma("unroll") for (int j = 0; j < 3; ++j)                              \
        wreg[j] = *(const u32x4*)(wsrc + (size_t)j * 32 * D_MODEL + (K0));     \
} while (0)

#define DSWRITE(BUF) do {                                                      \
    float* XB = &xs[BUF][0]; unsigned short* WB = &wls[BUF][0];                \
    _Pragma("unroll") for (int j = 0; j < 4; ++j)                              \
        *(f32x4*)(XB + ((t >> 4) + j * 16) * XSTR + (t & 15) * 4) = xreg[j];   \
    _Pragma("unroll") for (int j = 0; j < 3; ++j)                              \
        *(u32x4*)(WB + ((t >> 3) + j * 32) * WSTR + (t & 7) * 8) = wreg[j];    \
} while (0)

#define COMPUTE(BUF) do {                                                      \
    const float* XB = &xs[BUF][0]; const unsigned short* WB = &wls[BUF][0];    \
    _Pragma("unroll") for (int ks = 0; ks < 2; ++ks) {                         \
        s16x8 af[2];                                                           \
        _Pragma("unroll") for (int sub = 0; sub < 2; ++sub) {                  \
            const float* ap = XB + (wr * 32 + sub * 16 + lr) * XSTR + ks * 32 + lg * 8; \
            f32x4 a0 = *(const f32x4*)ap, a1 = *(const f32x4*)(ap + 4);        \
            u32x4 pk;                                                          \
            pk[0] = cvtpk_bf16(a0[0], a0[1]); pk[1] = cvtpk_bf16(a0[2], a0[3]);\
            pk[2] = cvtpk_bf16(a1[0], a1[1]); pk[3] = cvtpk_bf16(a1[2], a1[3]);\
            af[sub] = __builtin_bit_cast(s16x8, pk);                           \
        }                                                                      \
        _Pragma("unroll") for (int tc = 0; tc < 3; ++tc) {                     \
            s16x8 bf = *(const s16x8*)(WB + (wc * 48 + tc * 16 + lr) * WSTR + ks * 32 + lg * 8); \
            acc[0][tc] = mfma16(af[0], bf, acc[0][tc]);                        \
            acc[1][tc] = mfma16(af[1], bf, acc[1][tc]);                        \
        }                                                                      \
    }                                                                          \
} while (0)

    // prologue: stage tile 0, issue tile 1
    GLOAD(0);
    DSWRITE(0);
    GLOAD(64);
    __syncthreads();

    for (int step = 0; step < 16; ++step) {
        const int cur = step & 1;
        if (step + 1 < 16) DSWRITE(cur ^ 1);         // write next tile (regs ready)
        if (step + 2 < 16) GLOAD((step + 2) * 64);   // issue loads 2 steps ahead
        COMPUTE(cur);
        __syncthreads();                             // one barrier per K-step
    }

#undef GLOAD
#undef DSWRITE
#undef COMPUTE

    // epilogue: bias + dtype-split writes
#pragma unroll
    for (int sub = 0; sub < 2; ++sub)
#pragma unroll
        for (int tc = 0; tc < 3; ++tc) {
            int col = nb * 96 + wc * 48 + tc * 16 + lr;
            float bias = (col < 64) ? bq[col] : (col < 128) ? bk[col - 64] : bv[col - 128];
#pragma unroll
            for (int r = 0; r < 4; ++r) {
                int row = mb * 64 + wr * 32 + sub * 16 + lg * 4 + r;   // = b*4096 + t
                float v = acc[sub][tc][r] + bias;
                if (col < 64) {
                    // scale = 1/sqrt(64) * log2(e): softmax in exp2 domain
                    q_ws[(size_t)row * 64 + col] = f2bf(v * 0.18033688011112042f);
                } else if (col < 128) {
                    k_ws[(size_t)row * 64 + (col - 64)] = f2bf(v);
                } else {
                    int b = row >> 12, tt = row & 4095;
                    vT_ws[(size_t)(b * 64 + (col - 128)) * SEQ_T + tt] = f2bf(v);
                }
            }
        }
}

// ---------------------------------------------------------------------------
// Kernel 2: causal flash attention, swapped-QK in-register softmax (32x32),
// exp2-domain.  EXACT round-12 structure (passed, attn 49.1us): grid 256,
// block=(b,p) with q-tiles qb=p and qb=127-p sequentially (129 KV-tiles per
// block), 16 waves, stride-16 KV split, K prefetched 1 tile ahead, V at use,
// direct normalized output.  ONLY addition: s_setprio(1) around the QK and
// PV MFMA clusters (T5: +4-7% on attn with phase-independent waves, m191;
// cannot affect semantics).
// ---------------------------------------------------------------------------
__global__ __launch_bounds__(1024, 4) void attn_kernel(
    const unsigned short* __restrict__ q_ws, const unsigned short* __restrict__ k_ws,
    const unsigned short* __restrict__ vT_ws, float* __restrict__ out)
{
    __shared__ float solds[8][32][66];               // 67.6 KiB
    __shared__ float sml[16][2][32];                 // 4 KiB
    const int lane = threadIdx.x & 63;
    const int w = threadIdx.x >> 6;                  // 0..15
    const int q = lane & 31;
    const int hi = lane >> 5;
    const int khalf = 4 * hi;
    // XCD-batch swizzle: batch = bits 1-2 of bid (pins K/V to an XCD pair).
    const int b = ((int)blockIdx.x & 7) >> 1;
    const int p = ((int)blockIdx.x >> 3) + (((int)blockIdx.x & 1) << 5);  // 0..63

#define PUBLISH(SLOT) do {                                                     \
    _Pragma("unroll") for (int i = 0; i < 16; ++i) {                           \
        int d = (i & 3) + 8 * (i >> 2) + khalf;                                \
        solds[SLOT][q][d] = o0[i];                                             \
        solds[SLOT][q][d + 32] = o1[i];                                        \
    }                                                                          \
    if (!hi) { sml[w][0][q] = m; sml[w][1][q] = lsum; }                        \
} while (0)

#define MERGE(SLOT, PW) do {                                                   \
    float mp = sml[PW][0][q], lp = sml[PW][1][q];                              \
    float M = fmaxf(m, mp);                                                    \
    float e = ex2(m - M), ep = ex2(mp - M);                                    \
    m = M; lsum = lsum * e + lp * ep;                                          \
    _Pragma("unroll") for (int i = 0; i < 16; ++i) {                           \
        int d = (i & 3) + 8 * (i >> 2) + khalf;                                \
        o0[i] = o0[i] * e + solds[SLOT][q][d] * ep;                            \
        o1[i] = o1[i] * e + solds[SLOT][q][d + 32] * ep;                       \
    }                                                                          \
} while (0)

    for (int half = 0; half < 2; ++half) {
        const int qb = (half == 0) ? p : 127 - p;
        const int q0 = SEQ_T - 32 * (qb + 1);
        const int ntiles = (q0 >> 5) + 1;

        const unsigned short* qrow = q_ws + ((size_t)(b * SEQ_T + q0 + q)) * 64 + hi * 8;
        s16x8 qf[4];
#pragma unroll
        for (int d = 0; d < 4; ++d) qf[d] = *(const s16x8*)(qrow + d * 16);

        f32x16 o0 = (f32x16)0.0f, o1 = (f32x16)0.0f;
        float m = -1e30f, lsum = 0.0f;

        const unsigned short* kbase = k_ws + ((size_t)(b * SEQ_T + q)) * 64 + hi * 8;
        const unsigned short* vb0 = vT_ws + ((size_t)(b * 64 + q)) * SEQ_T + hi * 8;
        const unsigned short* vb1 = vT_ws + ((size_t)(b * 64 + 32 + q)) * SEQ_T + hi * 8;

        int c = w;
        if (c < ntiles) {
            s16x8 kf[4];
            {
                const unsigned short* kp = kbase + (size_t)(c << 5) * 64;
#pragma unroll
                for (int d = 0; d < 4; ++d) kf[d] = *(const s16x8*)(kp + d * 16);
            }
            for (; c < ntiles; c += 16) {
                const int kv = c << 5;
                // ---- S^T = K Q^T (log2 domain) ----
                f32x16 s = (f32x16)0.0f;
                __builtin_amdgcn_s_setprio(1);
#pragma unroll
                for (int d = 0; d < 4; ++d) s = mfma32(kf[d], qf[d], s);
                __builtin_amdgcn_s_setprio(0);
                // ---- prefetch next K tile (stride 16) ----
                {
                    const int cn = (c + 16 < ntiles) ? c + 16 : 0;
                    const unsigned short* kp = kbase + (size_t)(cn << 5) * 64;
#pragma unroll
                    for (int d = 0; d < 4; ++d) kf[d] = *(const s16x8*)(kp + d * 16);
                }
                // ---- V^T A-fragments (issued here, consumed after softmax) ----
                s16x8 vf00 = *(const s16x8*)(vb0 + kv);
                s16x8 vf01 = *(const s16x8*)(vb0 + kv + 16);
                s16x8 vf10 = *(const s16x8*)(vb1 + kv);
                s16x8 vf11 = *(const s16x8*)(vb1 + kv + 16);
                // ---- causal mask (diagonal tile only) ----
                if (kv + 32 > q0) {
                    const int qg = q0 + q;
#pragma unroll
                    for (int i = 0; i < 16; ++i) {
                        int kk = kv + (i & 3) + 8 * (i >> 2) + khalf;
                        if (kk > qg) s[i] = -1e30f;
                    }
                }
                // ---- row max: tree + half-exchange (order-agnostic) ----
                float t0, t1;
                t0 = fmaxf(s[0], s[1]);   t1 = fmaxf(s[2], s[3]);   t0 = fmaxf(t0, t1);
                t1 = fmaxf(s[4], s[5]);   t1 = fmaxf(t1, fmaxf(s[6], s[7]));
                float t2 = fmaxf(fmaxf(s[8], s[9]), fmaxf(s[10], s[11]));
                float t3 = fmaxf(fmaxf(s[12], s[13]), fmaxf(s[14], s[15]));
                float mx = fmaxf(fmaxf(t0, t1), fmaxf(t2, t3));
                {
                    unsigned int r0, r1;
                    halfswap(__float_as_uint(mx), r0, r1);
                    mx = fmaxf(__uint_as_float(r0), __uint_as_float(r1));
                }
                const float mnew = fmaxf(m, mx);
                const float corr = ex2(m - mnew);
                m = mnew;
                // ---- P = 2^(S - m), row sum ----
                float rs = 0.0f;
#pragma unroll
                for (int i = 0; i < 16; ++i) {
                    float pv = ex2(s[i] - mnew);
                    s[i] = pv;
                    rs += pv;
                }
                {
                    unsigned int r0, r1;
                    halfswap(__float_as_uint(rs), r0, r1);
                    rs = __uint_as_float(r0) + __uint_as_float(r1);
                }
                lsum = lsum * corr + rs;
#pragma unroll
                for (int i = 0; i < 16; ++i) { o0[i] *= corr; o1[i] *= corr; }
                // ---- pack P -> B-fragments (cvt_pk; partner via r0^r1^own) ----
                unsigned int cc[8], pc[8];
#pragma unroll
                for (int i = 0; i < 8; ++i) cc[i] = cvtpk_bf16(s[2 * i], s[2 * i + 1]);
#pragma unroll
                for (int i = 0; i < 8; ++i) {
                    unsigned int r0, r1;
                    halfswap(cc[i], r0, r1);
                    pc[i] = r0 ^ r1 ^ cc[i];         // partner word, any convention
                }
                u32x4 w0, w1;
                w0[0] = hi ? pc[2] : cc[0]; w0[1] = hi ? pc[3] : cc[1];
                w0[2] = hi ? cc[2] : pc[0]; w0[3] = hi ? cc[3] : pc[1];
                w1[0] = hi ? pc[6] : cc[4]; w1[1] = hi ? pc[7] : cc[5];
                w1[2] = hi ? cc[6] : pc[4]; w1[3] = hi ? cc[7] : pc[5];
                s16x8 pb0 = __builtin_bit_cast(s16x8, w0);
                s16x8 pb1 = __builtin_bit_cast(s16x8, w1);
                // ---- O^T += V^T P^T ----
                __builtin_amdgcn_s_setprio(1);
                o0 = mfma32(vf00, pb0, o0);
                o0 = mfma32(vf01, pb1, o0);
                o1 = mfma32(vf10, pb0, o1);
                o1 = mfma32(vf11, pb1, o1);
                __builtin_amdgcn_s_setprio(0);
            }
        }

        // ---- cascade combine: 16 -> 8 -> 4 -> 1 ----
        if (w >= 8) PUBLISH(w - 8);
        __syncthreads();
        if (w < 8) MERGE(w, w + 8);
        __syncthreads();
        if (w >= 4 && w < 8) PUBLISH(w - 4);
        __syncthreads();
        if (w < 4) { MERGE(w, w + 4); PUBLISH(w); }
        __syncthreads();
        // ---- final: 1024 threads, 2 outputs each ----
        {
            const int qq = (int)threadIdx.x >> 5;
            const int dd = ((int)threadIdx.x & 31) * 2;
            float M = -1e30f;
#pragma unroll
            for (int ww = 0; ww < 4; ++ww) M = fmaxf(M, sml[ww][0][qq]);
            float L = 0.0f, O0 = 0.0f, O1 = 0.0f;
#pragma unroll
            for (int ww = 0; ww < 4; ++ww) {
                float e = ex2(sml[ww][0][qq] - M);
                L += sml[ww][1][qq] * e;
                O0 += solds[ww][qq][dd] * e;
                O1 += solds[ww][qq][dd + 1] * e;
            }
            f32x2 res; res[0] = O0 / L; res[1] = O1 / L;
            *(f32x2*)(out + ((size_t)(b * SEQ_T + q0 + qq)) * 64 + dd) = res;
        }
        __syncthreads();                             // solds reused by next half
    }
#undef PUBLISH
#undef MERGE
}

// ---------------------------------------------------------------------------
extern "C" void kernel_launch(void* const* d_in, const int* in_sizes, int n_in,
                              void* d_out, int out_size, void* d_ws, size_t ws_size,
                              hipStream_t stream) {
    const float* x  = (const float*)d_in[0];
    const float* wq = (const float*)d_in[1];
    const float* bq = (const float*)d_in[2];
    const float* wk = (const float*)d_in[3];
    const float* bk = (const float*)d_in[4];
    const float* wv = (const float*)d_in[5];
    const float* bv = (const float*)d_in[6];
    float* out = (float*)d_out;

    char* ws = (char*)d_ws;
    unsigned short* wT    = (unsigned short*)(ws);                       // 384 KiB
    unsigned short* q_ws  = (unsigned short*)(ws + 393216);              // 2 MiB
    unsigned short* k_ws  = (unsigned short*)(ws + 393216 + 2097152);    // 2 MiB
    unsigned short* vT_ws = (unsigned short*)(ws + 393216 + 2 * 2097152);// 2 MiB

    wconv_kernel<<<dim3(768), dim3(256), 0, stream>>>(wq, wk, wv, wT);
    qkv_kernel<<<dim3(512), dim3(256), 0, stream>>>(x, bq, bk, bv, wT, q_ws, k_ws, vT_ws);
    attn_kernel<<<dim3(256), dim3(1024), 0, stream>>>(q_ws, k_ws, vT_ws, out);
}

// Round 18
// 58.042 us; speedup vs baseline: 3.3582x; 1.3320x over previous
//
#include <hip/hip_runtime.h>
#include <hip/hip_bf16.h>

typedef __attribute__((ext_vector_type(2)))  float f32x2;
typedef __attribute__((ext_vector_type(4)))  float f32x4;
typedef __attribute__((ext_vector_type(16))) float f32x16;
typedef __attribute__((ext_vector_type(8)))  short s16x8;
typedef __attribute__((ext_vector_type(4)))  unsigned int u32x4;
typedef __attribute__((ext_vector_type(2)))  int i32x2;

#define D_MODEL 1024
#define D_HEAD  64
#define SEQ_T   4096

__device__ __forceinline__ unsigned short f2bf(float f) {
    unsigned int u = __float_as_uint(f);
    u += 0x7fffu + ((u >> 16) & 1u);
    return (unsigned short)(u >> 16);
}

__device__ __forceinline__ unsigned int cvtpk_bf16(float lo, float hi) {
    unsigned int r;
    asm("v_cvt_pk_bf16_f32 %0, %1, %2" : "=v"(r) : "v"(lo), "v"(hi));
    return r;
}

// raw 2^x (single v_exp_f32).  Scores are computed in log2 domain (log2e
// folded into the q pre-scale), so no per-element multiply is needed.
__device__ __forceinline__ float ex2(float x) {
#if __has_builtin(__builtin_amdgcn_exp2f)
    return __builtin_amdgcn_exp2f(x);
#else
    return exp2f(x);
#endif
}

// lane l <-> lane l^32 exchange.  Returns BOTH post-exchange words: per lane
// {r0, r1} == {x[l], x[l^32]} (order may be lane-dependent).  Consumers use
// order-agnostic ops (fmax/add) or r0^r1^x for the partner.  SSA builtin ->
// distinct result registers, no aliasing.  PROVEN round 10/11/12.
__device__ __forceinline__ void halfswap(unsigned int x,
                                         unsigned int& r0, unsigned int& r1) {
#if __has_builtin(__builtin_amdgcn_permlane32_swap)
    i32x2 r = __builtin_amdgcn_permlane32_swap((int)x, (int)x, false, false);
    r0 = (unsigned int)r[0];
    r1 = (unsigned int)r[1];
#else
    r0 = x;
    r1 = (unsigned int)__shfl_xor((int)x, 32);       // proven fallback
#endif
}

__device__ __forceinline__ f32x4 mfma16(s16x8 a, s16x8 b, f32x4 c) {
    return __builtin_amdgcn_mfma_f32_16x16x32_bf16(a, b, c, 0, 0, 0);
}
__device__ __forceinline__ f32x16 mfma32(s16x8 a, s16x8 b, f32x16 c) {
    return __builtin_amdgcn_mfma_f32_32x32x16_bf16(a, b, c, 0, 0, 0);
}

// ---------------------------------------------------------------------------
// Kernel 0: weights [1024][64] f32 (q,k,v) -> wT [192][1024] bf16 (transposed)
// ---------------------------------------------------------------------------
__global__ __launch_bounds__(256) void wconv_kernel(
    const float* __restrict__ wq, const float* __restrict__ wk,
    const float* __restrict__ wv, unsigned short* __restrict__ wT)
{
    int idx = blockIdx.x * 256 + threadIdx.x;        // [0, 3*65536)
    int mat = idx >> 16;
    int rem = idx & 65535;
    int k = rem >> 6, n = rem & 63;
    const float* w = (mat == 0) ? wq : (mat == 1) ? wk : wv;
    wT[(size_t)(mat * 64 + n) * D_MODEL + k] = f2bf(w[rem]);
}

// ---------------------------------------------------------------------------
// Kernel 1: fused QKV projection — 2-phase LDS GEMM (proven ~24us).
// STRIDES MUST KEEP 16B ROW ALIGNMENT: x [64][68] f32, wT [96][72] bf16.
// q pre-scaled by log2e/8.
// Round 17: K and V written in MFMA-FRAGMENT-TILED layout so the attention
// kernel's loads are fully coalesced (was: 32-line gathers = 4x L1<->L2
// line over-fetch, ~31us of attn's 49us):
//   kt[((b*128 + c)*4 + d)*512 + l*8 + e] = K[b][c*32+(l&31)][d*16+(l>>5)*8+e]
//   vt[((b*128 + c)*4 + f)*512 + l*8 + e] =
//        V[b][(f>>1)*32+(l&31)][c*32+(f&1)*16+(l>>5)*8+e]
// Fragment contents bit-identical to the old row-major/transposed layouts.
// ---------------------------------------------------------------------------
#define XSTR 68
#define WSTR 72
__global__ __launch_bounds__(256, 2) void qkv_kernel(
    const float* __restrict__ x,
    const float* __restrict__ bq, const float* __restrict__ bk,
    const float* __restrict__ bv,
    const unsigned short* __restrict__ wT,
    unsigned short* __restrict__ q_ws, unsigned short* __restrict__ k_ws,
    unsigned short* __restrict__ vT_ws)
{
    __shared__ float xs[2][64 * XSTR];               // 2 x 17408 B
    __shared__ unsigned short wls[2][96 * WSTR];     // 2 x 13824 B (61 KiB)
    const int t = threadIdx.x;
    const int lane = t & 63, w = t >> 6;
    const int wr = w >> 1, wc = w & 1;
    const int lr = lane & 15, lg = lane >> 4;
    const int mb = (int)blockIdx.x >> 1, nb = (int)blockIdx.x & 1;

    const float* xsrc = x + (size_t)(mb * 64 + (t >> 4)) * D_MODEL + (t & 15) * 4;
    const unsigned short* wsrc = wT + (size_t)(nb * 96 + (t >> 3)) * D_MODEL + (t & 7) * 8;

    f32x4 acc[2][3];
#pragma unroll
    for (int s = 0; s < 2; ++s)
#pragma unroll
        for (int c = 0; c < 3; ++c) acc[s][c] = (f32x4)0.0f;

    f32x4 xreg[4];
    u32x4 wreg[3];

#define GLOAD(K0) do {                                                         \
    _Pragma("unroll") for (int j = 0; j < 4; ++j)                              \
        xreg[j] = *(const f32x4*)(xsrc + (size_t)j * 16 * D_MODEL + (K0));     \
    _Pragma("unroll") for (int j = 0; j < 3; ++j)                              \
        wreg[j] = *(const u32x4*)(wsrc + (size_t)j * 32 * D_MODEL + (K0));     \
} while (0)

#define DSWRITE(BUF) do {                                                      \
    float* XB = &xs[BUF][0]; unsigned short* WB = &wls[BUF][0];                \
    _Pragma("unroll") for (int j = 0; j < 4; ++j)                              \
        *(f32x4*)(XB + ((t >> 4) + j * 16) * XSTR + (t & 15) * 4) = xreg[j];   \
    _Pragma("unroll") for (int j = 0; j < 3; ++j)                              \
        *(u32x4*)(WB + ((t >> 3) + j * 32) * WSTR + (t & 7) * 8) = wreg[j];    \
} while (0)

#define COMPUTE(BUF) do {                                                      \
    const float* XB = &xs[BUF][0]; const unsigned short* WB = &wls[BUF][0];    \
    _Pragma("unroll") for (int ks = 0; ks < 2; ++ks) {                         \
        s16x8 af[2];                                                           \
        _Pragma("unroll") for (int sub = 0; sub < 2; ++sub) {                  \
            const float* ap = XB + (wr * 32 + sub * 16 + lr) * XSTR + ks * 32 + lg * 8; \
            f32x4 a0 = *(const f32x4*)ap, a1 = *(const f32x4*)(ap + 4);        \
            u32x4 pk;                                                          \
            pk[0] = cvtpk_bf16(a0[0], a0[1]); pk[1] = cvtpk_bf16(a0[2], a0[3]);\
            pk[2] = cvtpk_bf16(a1[0], a1[1]); pk[3] = cvtpk_bf16(a1[2], a1[3]);\
            af[sub] = __builtin_bit_cast(s16x8, pk);                           \
        }                                                                      \
        _Pragma("unroll") for (int tc = 0; tc < 3; ++tc) {                     \
            s16x8 bf = *(const s16x8*)(WB + (wc * 48 + tc * 16 + lr) * WSTR + ks * 32 + lg * 8); \
            acc[0][tc] = mfma16(af[0], bf, acc[0][tc]);                        \
            acc[1][tc] = mfma16(af[1], bf, acc[1][tc]);                        \
        }                                                                      \
    }                                                                          \
} while (0)

    // prologue: stage tile 0, issue tile 1
    GLOAD(0);
    DSWRITE(0);
    GLOAD(64);
    __syncthreads();

    for (int step = 0; step < 16; ++step) {
        const int cur = step & 1;
        if (step + 1 < 16) DSWRITE(cur ^ 1);         // write next tile (regs ready)
        if (step + 2 < 16) GLOAD((step + 2) * 64);   // issue loads 2 steps ahead
        COMPUTE(cur);
        __syncthreads();                             // one barrier per K-step
    }

#undef GLOAD
#undef DSWRITE
#undef COMPUTE

    // epilogue: bias + dtype-split writes (K/V into fragment-tiled layouts)
#pragma unroll
    for (int sub = 0; sub < 2; ++sub)
#pragma unroll
        for (int tc = 0; tc < 3; ++tc) {
            int col = nb * 96 + wc * 48 + tc * 16 + lr;
            float bias = (col < 64) ? bq[col] : (col < 128) ? bk[col - 64] : bv[col - 128];
#pragma unroll
            for (int r = 0; r < 4; ++r) {
                int row = mb * 64 + wr * 32 + sub * 16 + lg * 4 + r;   // = b*4096 + t
                float v = acc[sub][tc][r] + bias;
                int bb = row >> 12, tt = row & 4095;
                int cc_ = tt >> 5;
                if (col < 64) {
                    // scale = 1/sqrt(64) * log2(e): softmax in exp2 domain
                    q_ws[(size_t)row * 64 + col] = f2bf(v * 0.18033688011112042f);
                } else if (col < 128) {
                    int kcol = col - 64;
                    int d = kcol >> 4, hi2 = (kcol >> 3) & 1, e = kcol & 7;
                    int l = (tt & 31) + 32 * hi2;
                    k_ws[(size_t)(((bb * 128 + cc_) * 4 + d) * 64 + l) * 8 + e] = f2bf(v);
                } else {
                    int h = col - 128;
                    int w32 = tt & 31;
                    int fb0 = (w32 >> 4) & 1, hi2 = (w32 >> 3) & 1, e = w32 & 7;
                    int f = ((h >> 5) << 1) | fb0;
                    int l = (h & 31) + 32 * hi2;
                    vT_ws[(size_t)(((bb * 128 + cc_) * 4 + f) * 64 + l) * 8 + e] = f2bf(v);
                }
            }
        }
}

// ---------------------------------------------------------------------------
// Kernel 2: causal flash attention, swapped-QK in-register softmax (32x32),
// exp2-domain.  Round-12 structure (grid 256, block=(b,p), q-tiles qb=p and
// qb=127-p sequentially = 129 KV-tiles/block, 16 waves, stride-16 KV split,
// K prefetched 1 tile ahead, V at use).
// Round 17: K/V read from the fragment-tiled layouts -> every load is a
// fully-coalesced contiguous 1KB dwordx4 (was 32-line gather; 4x line
// over-fetch eliminated, TA address work /32).  Fragment bits identical.
// ---------------------------------------------------------------------------
__global__ __launch_bounds__(1024, 4) void attn_kernel(
    const unsigned short* __restrict__ q_ws, const unsigned short* __restrict__ k_ws,
    const unsigned short* __restrict__ vT_ws, float* __restrict__ out)
{
    __shared__ float solds[8][32][66];               // 67.6 KiB
    __shared__ float sml[16][2][32];                 // 4 KiB
    const int lane = threadIdx.x & 63;
    const int w = threadIdx.x >> 6;                  // 0..15
    const int q = lane & 31;
    const int hi = lane >> 5;
    const int khalf = 4 * hi;
    // XCD-batch swizzle: batch = bits 1-2 of bid (pins K/V to an XCD pair).
    const int b = ((int)blockIdx.x & 7) >> 1;
    const int p = ((int)blockIdx.x >> 3) + (((int)blockIdx.x & 1) << 5);  // 0..63

#define PUBLISH(SLOT) do {                                                     \
    _Pragma("unroll") for (int i = 0; i < 16; ++i) {                           \
        int d = (i & 3) + 8 * (i >> 2) + khalf;                                \
        solds[SLOT][q][d] = o0[i];                                             \
        solds[SLOT][q][d + 32] = o1[i];                                        \
    }                                                                          \
    if (!hi) { sml[w][0][q] = m; sml[w][1][q] = lsum; }                        \
} while (0)

#define MERGE(SLOT, PW) do {                                                   \
    float mp = sml[PW][0][q], lp = sml[PW][1][q];                              \
    float M = fmaxf(m, mp);                                                    \
    float e = ex2(m - M), ep = ex2(mp - M);                                    \
    m = M; lsum = lsum * e + lp * ep;                                          \
    _Pragma("unroll") for (int i = 0; i < 16; ++i) {                           \
        int d = (i & 3) + 8 * (i >> 2) + khalf;                                \
        o0[i] = o0[i] * e + solds[SLOT][q][d] * ep;                            \
        o1[i] = o1[i] * e + solds[SLOT][q][d + 32] * ep;                       \
    }                                                                          \
} while (0)

    // fragment-tiled bases: 2048 elements (4 KB) per KV-tile
    const unsigned short* kt = k_ws + (size_t)(b * 128) * 2048;
    const unsigned short* vt = vT_ws + (size_t)(b * 128) * 2048;
    const int lane8 = lane * 8;

    for (int half = 0; half < 2; ++half) {
        const int qb = (half == 0) ? p : 127 - p;
        const int q0 = SEQ_T - 32 * (qb + 1);
        const int ntiles = (q0 >> 5) + 1;

        const unsigned short* qrow = q_ws + ((size_t)(b * SEQ_T + q0 + q)) * 64 + hi * 8;
        s16x8 qf[4];
#pragma unroll
        for (int d = 0; d < 4; ++d) qf[d] = *(const s16x8*)(qrow + d * 16);

        f32x16 o0 = (f32x16)0.0f, o1 = (f32x16)0.0f;
        float m = -1e30f, lsum = 0.0f;

        int c = w;
        if (c < ntiles) {
            s16x8 kf[4];
            {
                const unsigned short* kp = kt + (size_t)c * 2048 + lane8;
#pragma unroll
                for (int d = 0; d < 4; ++d) kf[d] = *(const s16x8*)(kp + d * 512);
            }
            for (; c < ntiles; c += 16) {
                const int kv = c << 5;
                // ---- S^T = K Q^T (log2 domain) ----
                f32x16 s = (f32x16)0.0f;
                __builtin_amdgcn_s_setprio(1);
#pragma unroll
                for (int d = 0; d < 4; ++d) s = mfma32(kf[d], qf[d], s);
                __builtin_amdgcn_s_setprio(0);
                // ---- prefetch next K tile (stride 16), coalesced ----
                {
                    const int cn = (c + 16 < ntiles) ? c + 16 : 0;
                    const unsigned short* kp = kt + (size_t)cn * 2048 + lane8;
#pragma unroll
                    for (int d = 0; d < 4; ++d) kf[d] = *(const s16x8*)(kp + d * 512);
                }
                // ---- V fragments (coalesced; in flight during softmax) ----
                const unsigned short* vp = vt + (size_t)c * 2048 + lane8;
                s16x8 vf00 = *(const s16x8*)(vp);
                s16x8 vf01 = *(const s16x8*)(vp + 512);
                s16x8 vf10 = *(const s16x8*)(vp + 1024);
                s16x8 vf11 = *(const s16x8*)(vp + 1536);
                // ---- causal mask (diagonal tile only) ----
                if (kv + 32 > q0) {
                    const int qg = q0 + q;
#pragma unroll
                    for (int i = 0; i < 16; ++i) {
                        int kk = kv + (i & 3) + 8 * (i >> 2) + khalf;
                        if (kk > qg) s[i] = -1e30f;
                    }
                }
                // ---- row max: tree + half-exchange (order-agnostic) ----
                float t0, t1;
                t0 = fmaxf(s[0], s[1]);   t1 = fmaxf(s[2], s[3]);   t0 = fmaxf(t0, t1);
                t1 = fmaxf(s[4], s[5]);   t1 = fmaxf(t1, fmaxf(s[6], s[7]));
                float t2 = fmaxf(fmaxf(s[8], s[9]), fmaxf(s[10], s[11]));
                float t3 = fmaxf(fmaxf(s[12], s[13]), fmaxf(s[14], s[15]));
                float mx = fmaxf(fmaxf(t0, t1), fmaxf(t2, t3));
                {
                    unsigned int r0, r1;
                    halfswap(__float_as_uint(mx), r0, r1);
                    mx = fmaxf(__uint_as_float(r0), __uint_as_float(r1));
                }
                const float mnew = fmaxf(m, mx);
                const float corr = ex2(m - mnew);
                m = mnew;
                // ---- P = 2^(S - m), row sum ----
                float rs = 0.0f;
#pragma unroll
                for (int i = 0; i < 16; ++i) {
                    float pv = ex2(s[i] - mnew);
                    s[i] = pv;
                    rs += pv;
                }
                {
                    unsigned int r0, r1;
                    halfswap(__float_as_uint(rs), r0, r1);
                    rs = __uint_as_float(r0) + __uint_as_float(r1);
                }
                lsum = lsum * corr + rs;
#pragma unroll
                for (int i = 0; i < 16; ++i) { o0[i] *= corr; o1[i] *= corr; }
                // ---- pack P -> B-fragments (cvt_pk; partner via r0^r1^own) ----
                unsigned int cc[8], pc[8];
#pragma unroll
                for (int i = 0; i < 8; ++i) cc[i] = cvtpk_bf16(s[2 * i], s[2 * i + 1]);
#pragma unroll
                for (int i = 0; i < 8; ++i) {
                    unsigned int r0, r1;
                    halfswap(cc[i], r0, r1);
                    pc[i] = r0 ^ r1 ^ cc[i];         // partner word, any convention
                }
                u32x4 w0, w1;
                w0[0] = hi ? pc[2] : cc[0]; w0[1] = hi ? pc[3] : cc[1];
                w0[2] = hi ? cc[2] : pc[0]; w0[3] = hi ? cc[3] : pc[1];
                w1[0] = hi ? pc[6] : cc[4]; w1[1] = hi ? pc[7] : cc[5];
                w1[2] = hi ? cc[6] : pc[4]; w1[3] = hi ? cc[7] : pc[5];
                s16x8 pb0 = __builtin_bit_cast(s16x8, w0);
                s16x8 pb1 = __builtin_bit_cast(s16x8, w1);
                // ---- O^T += V^T P^T ----
                __builtin_amdgcn_s_setprio(1);
                o0 = mfma32(vf00, pb0, o0);
                o0 = mfma32(vf01, pb1, o0);
                o1 = mfma32(vf10, pb0, o1);
                o1 = mfma32(vf11, pb1, o1);
                __builtin_amdgcn_s_setprio(0);
            }
        }

        // ---- cascade combine: 16 -> 8 -> 4 -> 1 ----
        if (w >= 8) PUBLISH(w - 8);
        __syncthreads();
        if (w < 8) MERGE(w, w + 8);
        __syncthreads();
        if (w >= 4 && w < 8) PUBLISH(w - 4);
        __syncthreads();
        if (w < 4) { MERGE(w, w + 4); PUBLISH(w); }
        __syncthreads();
        // ---- final: 1024 threads, 2 outputs each ----
        {
            const int qq = (int)threadIdx.x >> 5;
            const int dd = ((int)threadIdx.x & 31) * 2;
            float M = -1e30f;
#pragma unroll
            for (int ww = 0; ww < 4; ++ww) M = fmaxf(M, sml[ww][0][qq]);
            float L = 0.0f, O0 = 0.0f, O1 = 0.0f;
#pragma unroll
            for (int ww = 0; ww < 4; ++ww) {
                float e = ex2(sml[ww][0][qq] - M);
                L += sml[ww][1][qq] * e;
                O0 += solds[ww][qq][dd] * e;
                O1 += solds[ww][qq][dd + 1] * e;
            }
            f32x2 res; res[0] = O0 / L; res[1] = O1 / L;
            *(f32x2*)(out + ((size_t)(b * SEQ_T + q0 + qq)) * 64 + dd) = res;
        }
        __syncthreads();                             // solds reused by next half
    }
#undef PUBLISH
#undef MERGE
}

// ---------------------------------------------------------------------------
extern "C" void kernel_launch(void* const* d_in, const int* in_sizes, int n_in,
                              void* d_out, int out_size, void* d_ws, size_t ws_size,
                              hipStream_t stream) {
    const float* x  = (const float*)d_in[0];
    const float* wq = (const float*)d_in[1];
    const float* bq = (const float*)d_in[2];
    const float* wk = (const float*)d_in[3];
    const float* bk = (const float*)d_in[4];
    const float* wv = (const float*)d_in[5];
    const float* bv = (const float*)d_in[6];
    float* out = (float*)d_out;

    char* ws = (char*)d_ws;
    unsigned short* wT    = (unsigned short*)(ws);                       // 384 KiB
    unsigned short* q_ws  = (unsigned short*)(ws + 393216);              // 2 MiB
    unsigned short* k_ws  = (unsigned short*)(ws + 393216 + 2097152);    // 2 MiB (tiled)
    unsigned short* vT_ws = (unsigned short*)(ws + 393216 + 2 * 2097152);// 2 MiB (tiled)

    wconv_kernel<<<dim3(768), dim3(256), 0, stream>>>(wq, wk, wv, wT);
    qkv_kernel<<<dim3(512), dim3(256), 0, stream>>>(x, bq, bk, bv, wT, q_ws, k_ws, vT_ws);
    attn_kernel<<<dim3(256), dim3(1024), 0, stream>>>(q_ws, k_ws, vT_ws, out);
}